// Round 1
// baseline (72.039 us; speedup 1.0000x reference)
//
#include <hip/hip_runtime.h>

#define SIGMA 0.1f
#define RHO   10.0f
#define B     8
#define F     64
#define ROWS_PER_BLOCK 4

// 1024 blocks x 256 threads; wave w handles row = blockIdx*4 + w.
// All 4 rows of a block belong to the same (b1,b2) pair (4 | 64).
// Emits per-block partial of:  sum_rows (pos_divide/pos_cnt) * (1/F) * label[pair]
//
// R1: branchless fully-unrolled k-loop. Predicates live in wave-uniform 64-bit
// ballot masks (SGPR; consumed at compile-time-constant shifts -> pure SALU on
// the scalar pipe). sim row is read 4-at-a-time via broadcast ds_read_b128.
// Select arithmetic is arranged to be bitwise-identical to the branchy version:
//   pos-k:    all += ph;  fmaf(0,ql,all) is exact no-op;       pos += ph
//   nonly-k:  all += 0;   fmaf(1.0,ql,all) == all+ql exactly;  pos += 0
//   neither:  all += 0;   fmaf(0,ql,all) no-op
__global__ __launch_bounds__(256) void row_kernel(
    const float* __restrict__ sim,
    const float* __restrict__ pos,
    const float* __restrict__ neg,
    const float* __restrict__ label,
    float* __restrict__ partial)   // [1024]
{
    const int lane = threadIdx.x & 63;
    const int w    = threadIdx.x >> 6;
    const int row  = blockIdx.x * ROWS_PER_BLOCK + w;
    const int pair = row >> 6;               // row / F

    __shared__ __align__(16) float ls[ROWS_PER_BLOCK][F];
    __shared__ float psum[ROWS_PER_BLOCK];

    const size_t base = (size_t)row * F;
    const float sj = sim[base + lane];
    const float pj = pos[base + lane];
    const float nj = neg[base + lane];
    ls[w][lane] = sj;                        // wave-synchronous; LDS ops in-order per wave

    // wave-uniform 64-bit predicate masks (SGPR-resident)
    const unsigned long long pmask = __ballot(pj > 0.5f);
    const unsigned long long nonly = __ballot(nj > 0.5f) & ~pmask;

    float all_acc = 0.0f;
    float pos_acc = 0.0f;

    // Branchless per-k body. K is a compile-time constant after full unroll,
    // so the mask extracts are SALU (s_lshr/s_and/s_cselect) feeding VALU as
    // scalar operands. Diagonal k==lane: pos path d==0 -> ph=0; nonly path
    // implies pj==0 whose row term is annihilated below.
    #define PROC(SK, K) do {                                                  \
        const float prho = ((pmask >> (K)) & 1ull) ? RHO  : 0.0f;             \
        const float nf   = ((nonly >> (K)) & 1ull) ? 1.0f : 0.0f;             \
        const float d    = (SK) - sj;                                         \
        const float xs   = d * (1.0f / SIGMA);                                \
        const float t    = xs + 1.0f;                                         \
        const float tc   = fmaxf(t, 0.0f);                                    \
        const float ql   = (d > 0.0f) ? fmaf(2.0f, xs, 1.0f) : tc * tc;       \
        const float ph   = (d > 0.0f) ? prho : 0.0f;                          \
        all_acc += ph;                                                        \
        all_acc  = fmaf(nf, ql, all_acc);                                     \
        pos_acc += ph;                                                        \
    } while (0)

    const float4* __restrict__ s4 = reinterpret_cast<const float4*>(ls[w]);
    #pragma unroll
    for (int kk = 0; kk < F / 4; ++kk) {
        const float4 sv = s4[kk];            // one broadcast ds_read_b128 = 4 k values
        const int k0 = kk * 4;
        PROC(sv.x, k0 + 0);
        PROC(sv.y, k0 + 1);
        PROC(sv.z, k0 + 2);
        PROC(sv.w, k0 + 3);
    }
    #undef PROC

    const float all_rk = all_acc + 1.0f;     // >= 1, no div hazard
    const float pos_rk = pos_acc + 1.0f;

    float term = (pj > 0.5f) ? (pos_rk / all_rk) : 0.0f;
    float cntv = (pj > 0.5f) ? 1.0f : 0.0f;

    #pragma unroll
    for (int off = 32; off > 0; off >>= 1) {
        term += __shfl_down(term, off, 64);
        cntv += __shfl_down(cntv, off, 64);
    }

    if (lane == 0) psum[w] = term / cntv;    // this row's pos_divide/pos_cnt
    __syncthreads();

    if (threadIdx.x == 0) {
        const float lab = label[pair];
        const float s = psum[0] + psum[1] + psum[2] + psum[3];
        partial[blockIdx.x] = s * (1.0f / F) * lab;
    }
}

// 1 block x 256 threads: num = sum(partial[0..1023]); den = sum(label[0..63]);
// out = 1 - num/den
__global__ __launch_bounds__(256) void finish_kernel(
    const float* __restrict__ partial,
    const float* __restrict__ label,
    float* __restrict__ out)
{
    const int t    = threadIdx.x;
    const int lane = t & 63;
    const int w    = t >> 6;

    const float4 v = ((const float4*)partial)[t];   // coalesced, 16 B/lane
    float s = v.x + v.y + v.z + v.w;
    #pragma unroll
    for (int off = 32; off > 0; off >>= 1) s += __shfl_down(s, off, 64);

    __shared__ float sm[4];
    if (lane == 0) sm[w] = s;
    __syncthreads();

    if (t < 64) {
        float den = label[t];
        #pragma unroll
        for (int off = 32; off > 0; off >>= 1) den += __shfl_down(den, off, 64);
        if (t == 0) {
            const float num = sm[0] + sm[1] + sm[2] + sm[3];
            out[0] = 1.0f - num / den;
        }
    }
}

extern "C" void kernel_launch(void* const* d_in, const int* in_sizes, int n_in,
                              void* d_out, int out_size, void* d_ws, size_t ws_size,
                              hipStream_t stream)
{
    const float* sim   = (const float*)d_in[0];  // [B,B,F,F]
    const float* pos   = (const float*)d_in[1];  // [B,B,F,F]
    const float* neg   = (const float*)d_in[2];  // [B,B,F,F]
    const float* label = (const float*)d_in[3];  // [B,B]
    float*       out   = (float*)d_out;          // scalar
    float*       part  = (float*)d_ws;           // [1024] partials

    row_kernel<<<(B * B * F) / ROWS_PER_BLOCK, 256, 0, stream>>>(sim, pos, neg, label, part);
    finish_kernel<<<1, 256, 0, stream>>>(part, label, out);
}